// Round 9
// baseline (211.877 us; speedup 1.0000x reference)
//
#include <hip/hip_runtime.h>

#define SEG 24
#define DD  32
#define HEPS 1e-7f
#define N_ITERS 10

typedef _Float16 h2 __attribute__((ext_vector_type(2)));
typedef __fp16   f16v2 __attribute__((ext_vector_type(2)));

__device__ __forceinline__ float frcp(float x) { return __builtin_amdgcn_rcpf(x); }

__device__ __forceinline__ float qx1(float x) {
    return __int_as_float(__builtin_amdgcn_mov_dpp(__float_as_int(x), 0xB1, 0xF, 0xF, true));
}
__device__ __forceinline__ float qx2(float x) {
    return __int_as_float(__builtin_amdgcn_mov_dpp(__float_as_int(x), 0x4E, 0xF, 0xF, true));
}
__device__ __forceinline__ float qsum(float x) {
    x += qx1(x);
    x += qx2(x);
    return x;
}

__device__ __forceinline__ float acosh_coef(float a) {
    float am = fmaf(a, a, -1.0f);
    float s  = sqrtf(am);
    return __logf(a + s) * frcp(s);
}

__device__ __forceinline__ float edot8(const float a[8], const float b[8]) {
    float x = fmaf(a[0], b[0], a[1] * b[1]);
    float y = fmaf(a[2], b[2], a[3] * b[3]);
    float z = fmaf(a[4], b[4], a[5] * b[5]);
    float w = fmaf(a[6], b[6], a[7] * b[7]);
    return qsum((x + y) + (z + w));
}

__device__ __forceinline__ unsigned pk_u32(float a, float b) {
    union { f16v2 f; unsigned u; } c;
    c.f = __builtin_amdgcn_cvt_pkrtz(a, b);
    return c.u;
}
__device__ __forceinline__ h2 pk_h2(float a, float b) {
    union { f16v2 f; h2 h; } c;
    c.f = __builtin_amdgcn_cvt_pkrtz(a, b);
    return c.h;
}
__device__ __forceinline__ h2 as_h2(unsigned u) {
    union { unsigned u; h2 h; } c; c.u = u; return c.h;
}

// ws layout (dwords): [0,1536) packed W f16x2 (s*384 + row*12 + j)
//                     [1536,1664) b f32 (s*32 + d) ; [1664] tanh(es)
#define WS_B_OFF 1536
#define WS_TS_OFF 1664

// ============ K0: pack W to f16x2, copy b, tanh(es) -> d_ws =================
__global__ __launch_bounds__(256)
void prep_kernel(const float* __restrict__ W0, const float* __restrict__ b0,
                 const float* __restrict__ W1, const float* __restrict__ b1,
                 const float* __restrict__ W2, const float* __restrict__ b2,
                 const float* __restrict__ W3, const float* __restrict__ b3,
                 const float* __restrict__ es, unsigned* __restrict__ ws)
{
    const int t = blockIdx.x * blockDim.x + threadIdx.x;
    const float* Ws[4] = { W0, W1, W2, W3 };
    const float* bs[4] = { b0, b1, b2, b3 };
    if (t < 1536) {
        int s = t / 384, rem = t % 384, r = rem / 12, j = rem % 12;
        float a = Ws[s][r * SEG + 2 * j];
        float b = Ws[s][r * SEG + 2 * j + 1];
        ws[t] = pk_u32(a, b);
    } else if (t < 1664) {
        int p = t - 1536;
        reinterpret_cast<float*>(ws)[WS_B_OFF + p] = bs[p / 32][p % 32];
    } else if (t == 1664) {
        reinterpret_cast<float*>(ws)[WS_TS_OFF] = tanhf(es[0]);
    }
}

// ============ K1: fully fused, 4 lanes per item =============================
#define GMV(o0,o1,o2,o3,o4, v0,v1,v2,v3,v4)                                   \
    o0 = fmaf(G00,(v0), fmaf(G01,(v1), fmaf(G02,(v2), fmaf(G03,(v3), nt0*(v4))))); \
    o1 = fmaf(G01,(v0), fmaf(G11,(v1), fmaf(G12,(v2), fmaf(G13,(v3), nt1*(v4))))); \
    o2 = fmaf(G02,(v0), fmaf(G12,(v1), fmaf(G22,(v2), fmaf(G23,(v3), nt2*(v4))))); \
    o3 = fmaf(G03,(v0), fmaf(G13,(v1), fmaf(G23,(v2), fmaf(G33,(v3), nt3*(v4))))); \
    o4 = fmaf(nt0,(v0), fmaf(nt1,(v1), fmaf(nt2,(v2), fmaf(nt3,(v3), -(v4)))));

#define DOT5(a0,a1,a2,a3,a4, c0,c1,c2,c3,c4) \
    fmaf((a0),(c0), fmaf((a1),(c1), fmaf((a2),(c2), fmaf((a3),(c3), (a4)*(c4)))))

__global__ __launch_bounds__(256)
void fused_kernel(const float* __restrict__ x0, const float* __restrict__ x1,
                  const float* __restrict__ x2, const float* __restrict__ x3,
                  const unsigned* __restrict__ ws, const float* __restrict__ lw,
                  float* __restrict__ out, int n_items)
{
    const int T    = blockIdx.x * blockDim.x + threadIdx.x;
    const int item = T >> 2;
    const int sub  = T & 3;
    if (item >= n_items) return;

    const float m0 = (sub == 0) ? 1.0f : 0.0f;   // lane owns time dim d=0

    const float* wsf = reinterpret_cast<const float*>(ws);
    const float  ts  = wsf[WS_TS_OFF];

    // softmax over lorentz weights
    float l0 = lw[0], l1 = lw[1], l2 = lw[2], l3 = lw[3];
    float mxw = fmaxf(fmaxf(l0, l1), fmaxf(l2, l3));
    float e0 = __expf(l0 - mxw), e1 = __expf(l1 - mxw),
          e2 = __expf(l2 - mxw), e3 = __expf(l3 - mxw);
    float winv = frcp(e0 + e1 + e2 + e3);
    float w4a[4] = { e0 * winv, e1 * winv, e2 * winv, e3 * winv };

    const float* xs[4] = { x0, x1, x2, x3 };
    const size_t osz   = (size_t)n_items * DD;
    const int    row0  = sub * 8;

    float hv[4][8];
    float tau[4];

    // ---- encode + to_hyperbolic per stream; h stays in registers ----
    #pragma unroll
    for (int s = 0; s < 4; ++s) {
        // seg: quad-uniform float4 loads (4 lanes read same addr -> 1 line)
        const float4* sp = reinterpret_cast<const float4*>(xs[s] + (size_t)item * SEG);
        h2 sp2[SEG / 2];
        #pragma unroll
        for (int j = 0; j < SEG / 4; ++j) {
            float4 v = sp[j];
            sp2[2*j]   = pk_h2(v.x, v.y);
            sp2[2*j+1] = pk_h2(v.z, v.w);
        }

        // matvec slice: rows [row0, row0+8), f16 dot2, f32 accumulate
        const unsigned* wp = ws + s * 384 + row0 * 12;
        const float*    bp = wsf + WS_B_OFF + s * 32 + row0;
        float u[8];
        #pragma unroll
        for (int r = 0; r < 8; ++r) {
            const uint4* w4p = reinterpret_cast<const uint4*>(wp + r * 12);
            uint4 wa = w4p[0], wb = w4p[1], wc = w4p[2];
            float z = bp[r];
            z = __builtin_amdgcn_fdot2(sp2[0],  as_h2(wa.x), z, false);
            z = __builtin_amdgcn_fdot2(sp2[1],  as_h2(wa.y), z, false);
            z = __builtin_amdgcn_fdot2(sp2[2],  as_h2(wa.z), z, false);
            z = __builtin_amdgcn_fdot2(sp2[3],  as_h2(wa.w), z, false);
            z = __builtin_amdgcn_fdot2(sp2[4],  as_h2(wb.x), z, false);
            z = __builtin_amdgcn_fdot2(sp2[5],  as_h2(wb.y), z, false);
            z = __builtin_amdgcn_fdot2(sp2[6],  as_h2(wb.z), z, false);
            z = __builtin_amdgcn_fdot2(sp2[7],  as_h2(wb.w), z, false);
            z = __builtin_amdgcn_fdot2(sp2[8],  as_h2(wc.x), z, false);
            z = __builtin_amdgcn_fdot2(sp2[9],  as_h2(wc.y), z, false);
            z = __builtin_amdgcn_fdot2(sp2[10], as_h2(wc.z), z, false);
            z = __builtin_amdgcn_fdot2(sp2[11], as_h2(wc.w), z, false);
            u[r] = z * ts;
        }

        // safe_expmap0: <u,u>_L partial; time lane subtracts 2*u0^2
        float a = 0.0f;
        #pragma unroll
        for (int j = 0; j < 8; ++j) a = fmaf(u[j], u[j], a);
        a = fmaf(-2.0f * u[0] * u[0], m0, a);
        float sq  = fmaxf(qsum(a), 1e-12f);
        float nrm = sqrtf(sq);
        float ep  = __expf(nrm), em = frcp(ep);
        float sh  = 0.5f * (ep - em);
        float sc  = sh * frcp(fmaxf(nrm, HEPS));

        float b2 = 0.0f;
        #pragma unroll
        for (int j = 0; j < 8; ++j) {
            float yv = sc * u[j];
            hv[s][j] = yv;
            b2 = fmaf(yv, yv, b2);
        }
        b2 = fmaf(-hv[s][0] * hv[s][0], m0, b2);   // space norm excludes d=0
        float ss    = qsum(b2);
        float tcomp = sqrtf(1.0f + ss);            // projx time comp (quad-uniform)
        tau[s] = tcomp;
        if (sub == 0) hv[s][0] = tcomp;

        // coalesced store: lane covers 32 B, quad covers the 128 B item row
        float* op = out + (size_t)s * osz + (size_t)item * DD + row0;
        reinterpret_cast<float4*>(op)[0] =
            make_float4(hv[s][0], hv[s][1], hv[s][2], hv[s][3]);
        reinterpret_cast<float4*>(op)[1] =
            make_float4(hv[s][4], hv[s][5], hv[s][6], hv[s][7]);
    }

    // ---- Gram: 10 Euclidean dots via quad reduce ----
    float tau0 = tau[0], tau1 = tau[1], tau2 = tau[2], tau3 = tau[3];
    float d00 = edot8(hv[0], hv[0]);
    float d01 = edot8(hv[0], hv[1]);
    float d02 = edot8(hv[0], hv[2]);
    float d03 = edot8(hv[0], hv[3]);
    float d11 = edot8(hv[1], hv[1]);
    float d12 = edot8(hv[1], hv[2]);
    float d13 = edot8(hv[1], hv[3]);
    float d22 = edot8(hv[2], hv[2]);
    float d23 = edot8(hv[2], hv[3]);
    float d33 = edot8(hv[3], hv[3]);

    float G00 = fmaf(-2.0f*tau0, tau0, d00);
    float G01 = fmaf(-2.0f*tau0, tau1, d01);
    float G02 = fmaf(-2.0f*tau0, tau2, d02);
    float G03 = fmaf(-2.0f*tau0, tau3, d03);
    float G11 = fmaf(-2.0f*tau1, tau1, d11);
    float G12 = fmaf(-2.0f*tau1, tau2, d12);
    float G13 = fmaf(-2.0f*tau1, tau3, d13);
    float G22 = fmaf(-2.0f*tau2, tau2, d22);
    float G23 = fmaf(-2.0f*tau2, tau3, d23);
    float G33 = fmaf(-2.0f*tau3, tau3, d33);
    float nt0 = -tau0, nt1 = -tau1, nt2 = -tau2, nt3 = -tau3;

    // ---- fusion init in 5-d coordinates ----
    float b0v, b1v, b2v, b3v, b4v, g0, g1, g2, g3, g4;
    {
        float al0 = fmaxf(tau0, 1.0f + HEPS);
        float al1 = fmaxf(tau1, 1.0f + HEPS);
        float al2 = fmaxf(tau2, 1.0f + HEPS);
        float al3 = fmaxf(tau3, 1.0f + HEPS);
        float cc0 = w4a[0] * acosh_coef(al0);
        float cc1 = w4a[1] * acosh_coef(al1);
        float cc2 = w4a[2] * acosh_coef(al2);
        float cc3 = w4a[3] * acosh_coef(al3);
        b0v = cc0; b1v = cc1; b2v = cc2; b3v = cc3;
        b4v = -DOT5(cc0, cc1, cc2, cc3, 0.0f, al0, al1, al2, al3, 0.0f);

        GMV(g0, g1, g2, g3, g4, b0v, b1v, b2v, b3v, b4v);
        float gq = DOT5(g0, g1, g2, g3, g4, b0v, b1v, b2v, b3v, b4v);
        float sq = fmaxf(gq, 1e-12f);
        float nrm = sqrtf(sq);
        float ep = __expf(nrm), em = frcp(ep);
        float ch = 0.5f * (ep + em);
        float sc = 0.5f * (ep - em) * frcp(fmaxf(nrm, HEPS));
        b0v *= sc; b1v *= sc; b2v *= sc; b3v *= sc;
        b4v = fmaf(sc, b4v, ch);

        GMV(g0, g1, g2, g3, g4, b0v, b1v, b2v, b3v, b4v);
        float xx = DOT5(g0, g1, g2, g3, g4, b0v, b1v, b2v, b3v, b4v);
        float xt = DOT5(b0v, b1v, b2v, b3v, b4v, tau0, tau1, tau2, tau3, 1.0f);
        float tc = sqrtf(fmaf(xt, xt, 1.0f + xx));
        float dl = tc - xt;
        b4v += dl;
        g0 = fmaf(dl, nt0, g0); g1 = fmaf(dl, nt1, g1);
        g2 = fmaf(dl, nt2, g2); g3 = fmaf(dl, nt3, g3);
        g4 -= dl;
    }

    // ---- Frechet refinement, 10 iters in 5-d (invariant: g = G*beta) ----
    for (int it = 0; it < N_ITERS; ++it) {
        float al0 = fmaxf(-g0, 1.0f + HEPS);
        float al1 = fmaxf(-g1, 1.0f + HEPS);
        float al2 = fmaxf(-g2, 1.0f + HEPS);
        float al3 = fmaxf(-g3, 1.0f + HEPS);
        float cc0 = w4a[0] * acosh_coef(al0);
        float cc1 = w4a[1] * acosh_coef(al1);
        float cc2 = w4a[2] * acosh_coef(al2);
        float cc3 = w4a[3] * acosh_coef(al3);
        float S = DOT5(cc0, cc1, cc2, cc3, 0.0f, al0, al1, al2, al3, 0.0f);

        float gm0 = fmaf(-S, b0v, cc0);
        float gm1 = fmaf(-S, b1v, cc1);
        float gm2 = fmaf(-S, b2v, cc2);
        float gm3 = fmaf(-S, b3v, cc3);
        float gm4 = -S * b4v;

        float Gg0, Gg1, Gg2, Gg3, Gg4;
        GMV(Gg0, Gg1, Gg2, Gg3, Gg4, gm0, gm1, gm2, gm3, gm4);
        float qq = DOT5(Gg0, Gg1, Gg2, Gg3, Gg4, gm0, gm1, gm2, gm3, gm4);

        float sq = fmaxf(0.25f * qq, 1e-12f);
        float nrm = sqrtf(sq);
        float ep = __expf(nrm), em = frcp(ep);
        float ch = 0.5f * (ep + em);
        float sc = 0.25f * (ep - em) * frcp(fmaxf(nrm, HEPS));

        b0v = fmaf(ch, b0v, sc * gm0);
        b1v = fmaf(ch, b1v, sc * gm1);
        b2v = fmaf(ch, b2v, sc * gm2);
        b3v = fmaf(ch, b3v, sc * gm3);
        b4v = fmaf(ch, b4v, sc * gm4);
        g0  = fmaf(ch, g0, sc * Gg0);
        g1  = fmaf(ch, g1, sc * Gg1);
        g2  = fmaf(ch, g2, sc * Gg2);
        g3  = fmaf(ch, g3, sc * Gg3);
        g4  = fmaf(ch, g4, sc * Gg4);

        float xx = DOT5(g0, g1, g2, g3, g4, b0v, b1v, b2v, b3v, b4v);
        float xt = DOT5(b0v, b1v, b2v, b3v, b4v, tau0, tau1, tau2, tau3, 1.0f);
        float tc = sqrtf(fmaf(xt, xt, 1.0f + xx));
        float dl = tc - xt;
        b4v += dl;
        g0 = fmaf(dl, nt0, g0); g1 = fmaf(dl, nt1, g1);
        g2 = fmaf(dl, nt2, g2); g3 = fmaf(dl, nt3, g3);
        g4 -= dl;
    }

    // ---- reconstruction from registers ----
    float r[8];
    #pragma unroll
    for (int j = 0; j < 8; ++j)
        r[j] = fmaf(b0v, hv[0][j], fmaf(b1v, hv[1][j],
               fmaf(b2v, hv[2][j], b3v * hv[3][j])));
    if (sub == 0) r[0] += b4v;

    float* po = out + (size_t)4 * osz + (size_t)item * DD + row0;
    reinterpret_cast<float4*>(po)[0] = make_float4(r[0], r[1], r[2], r[3]);
    reinterpret_cast<float4*>(po)[1] = make_float4(r[4], r[5], r[6], r[7]);
}

extern "C" void kernel_launch(void* const* d_in, const int* in_sizes, int n_in,
                              void* d_out, int out_size, void* d_ws, size_t ws_size,
                              hipStream_t stream)
{
    const float* x0 = (const float*)d_in[0];
    const float* x1 = (const float*)d_in[1];
    const float* x2 = (const float*)d_in[2];
    const float* x3 = (const float*)d_in[3];
    const float* W0 = (const float*)d_in[4];
    const float* b0 = (const float*)d_in[5];
    const float* W1 = (const float*)d_in[6];
    const float* b1 = (const float*)d_in[7];
    const float* W2 = (const float*)d_in[8];
    const float* b2 = (const float*)d_in[9];
    const float* W3 = (const float*)d_in[10];
    const float* b3 = (const float*)d_in[11];
    const float* es = (const float*)d_in[12];
    const float* lw = (const float*)d_in[13];

    const int n_items = in_sizes[0] / SEG;   // 262144
    const int block = 256;

    prep_kernel<<<7, block, 0, stream>>>(W0, b0, W1, b1, W2, b2, W3, b3,
                                         es, (unsigned*)d_ws);

    const int n_threads = n_items * 4;
    const int gx = (n_threads + block - 1) / block;
    fused_kernel<<<gx, block, 0, stream>>>(x0, x1, x2, x3,
                                           (const unsigned*)d_ws, lw,
                                           (float*)d_out, n_items);
}

// Round 10
// 133.705 us; speedup vs baseline: 1.5847x; 1.5847x over previous
//
#include <hip/hip_runtime.h>

#define SEG 24
#define DD  32
#define HEPS 1e-7f
#define N_ITERS 10

typedef _Float16 h2 __attribute__((ext_vector_type(2)));
typedef __fp16   f16v2 __attribute__((ext_vector_type(2)));

__device__ __forceinline__ float frcp(float x) { return __builtin_amdgcn_rcpf(x); }

__device__ __forceinline__ float qx1(float x) {
    return __int_as_float(__builtin_amdgcn_mov_dpp(__float_as_int(x), 0xB1, 0xF, 0xF, true));
}
__device__ __forceinline__ float qx2(float x) {
    return __int_as_float(__builtin_amdgcn_mov_dpp(__float_as_int(x), 0x4E, 0xF, 0xF, true));
}
__device__ __forceinline__ float qsum(float x) {
    x += qx1(x);
    x += qx2(x);
    return x;
}

__device__ __forceinline__ float acosh_coef(float a) {
    float am = fmaf(a, a, -1.0f);
    float s  = sqrtf(am);
    return __logf(a + s) * frcp(s);
}

__device__ __forceinline__ float edot8(const float a[8], const float b[8]) {
    float x = fmaf(a[0], b[0], a[1] * b[1]);
    float y = fmaf(a[2], b[2], a[3] * b[3]);
    float z = fmaf(a[4], b[4], a[5] * b[5]);
    float w = fmaf(a[6], b[6], a[7] * b[7]);
    return qsum((x + y) + (z + w));
}

__device__ __forceinline__ unsigned pk_u32(float a, float b) {
    union { f16v2 f; unsigned u; } c;
    c.f = __builtin_amdgcn_cvt_pkrtz(a, b);
    return c.u;
}
__device__ __forceinline__ h2 pk_h2(float a, float b) {
    union { f16v2 f; h2 h; } c;
    c.f = __builtin_amdgcn_cvt_pkrtz(a, b);
    return c.h;
}
__device__ __forceinline__ h2 as_h2(unsigned u) {
    union { unsigned u; h2 h; } c; c.u = u; return c.h;
}

// ws layout (dwords): [0,1536) packed W f16x2 (s*384 + row*12 + j)
//                     [1536,1664) b f32 (s*32 + d) ; [1664] tanh(es)
#define WS_B_OFF 1536
#define WS_TS_OFF 1664

// ============ K0: pack W to f16x2, copy b, tanh(es) -> d_ws =================
__global__ __launch_bounds__(256)
void prep_kernel(const float* __restrict__ W0, const float* __restrict__ b0,
                 const float* __restrict__ W1, const float* __restrict__ b1,
                 const float* __restrict__ W2, const float* __restrict__ b2,
                 const float* __restrict__ W3, const float* __restrict__ b3,
                 const float* __restrict__ es, unsigned* __restrict__ ws)
{
    const int t = blockIdx.x * blockDim.x + threadIdx.x;
    const float* Ws[4] = { W0, W1, W2, W3 };
    const float* bs[4] = { b0, b1, b2, b3 };
    if (t < 1536) {
        int s = t / 384, rem = t % 384, r = rem / 12, j = rem % 12;
        float a = Ws[s][r * SEG + 2 * j];
        float b = Ws[s][r * SEG + 2 * j + 1];
        ws[t] = pk_u32(a, b);
    } else if (t < 1664) {
        int p = t - 1536;
        reinterpret_cast<float*>(ws)[WS_B_OFF + p] = bs[p / 32][p % 32];
    } else if (t == 1664) {
        reinterpret_cast<float*>(ws)[WS_TS_OFF] = tanhf(es[0]);
    }
}

// ============ K1: encode via fdot2; LDS-staged coalesced h stores ===========
__global__ __launch_bounds__(256)
void encode_kernel(const float* __restrict__ x0, const float* __restrict__ x1,
                   const float* __restrict__ x2, const float* __restrict__ x3,
                   const unsigned* __restrict__ ws,
                   float* __restrict__ out, int n_items)
{
    __shared__ float lds[256 * DD];                 // 32 KB h-staging tile

    const int tid   = threadIdx.x;
    const int item0 = blockIdx.x * 256;
    const int item  = item0 + tid;
    const int s     = blockIdx.y;                   // wave-uniform stream id

    const float* xp;
    if      (s == 0) xp = x0;
    else if (s == 1) xp = x1;
    else if (s == 2) xp = x2;
    else             xp = x3;

    const unsigned* W2p = ws + (size_t)s * 384;     // s_load source
    const float*    B2p = reinterpret_cast<const float*>(ws) + WS_B_OFF + s * 32;
    const float     ts  = reinterpret_cast<const float*>(ws)[WS_TS_OFF];

    if (item < n_items) {
        // load segment (f32) and pack to f16x2
        float seg[SEG];
        const float4* sp = reinterpret_cast<const float4*>(xp + (size_t)item * SEG);
        #pragma unroll
        for (int j = 0; j < SEG / 4; ++j) {
            float4 v = sp[j];
            seg[4*j+0] = v.x; seg[4*j+1] = v.y; seg[4*j+2] = v.z; seg[4*j+3] = v.w;
        }
        h2 sp2[SEG / 2];
        #pragma unroll
        for (int j = 0; j < SEG / 2; ++j)
            sp2[j] = pk_h2(seg[2*j], seg[2*j+1]);

        float u[DD];
        #pragma unroll
        for (int d = 0; d < DD; ++d) {
            float z = B2p[d];                        // wave-uniform -> s_load
            #pragma unroll
            for (int j = 0; j < SEG / 2; ++j)
                z = __builtin_amdgcn_fdot2(sp2[j], as_h2(W2p[d * 12 + j]), z, false);
            u[d] = z * ts;
        }

        // <u,u>_L = sum(u^2) - 2*u0^2, 4-way partials
        float q0 = 0.f, q1 = 0.f, q2 = 0.f, q3 = 0.f;
        #pragma unroll
        for (int d = 0; d < DD; d += 4) {
            q0 = fmaf(u[d+0], u[d+0], q0);
            q1 = fmaf(u[d+1], u[d+1], q1);
            q2 = fmaf(u[d+2], u[d+2], q2);
            q3 = fmaf(u[d+3], u[d+3], q3);
        }
        float sq = (q0 + q1) + (q2 + q3) - 2.0f * u[0] * u[0];
        sq = fmaxf(sq, 1e-12f);
        float nrm = sqrtf(sq);
        float ep = __expf(nrm), em = frcp(ep);
        float sh = 0.5f * (ep - em);
        float sc = sh * frcp(fmaxf(nrm, HEPS));

        float r0 = 0.f, r1 = 0.f, r2 = 0.f, r3 = 0.f;
        #pragma unroll
        for (int d = 1; d < DD; ++d) {
            float yv = sc * u[d];
            u[d] = yv;
            if ((d & 3) == 0) r0 = fmaf(yv, yv, r0);
            else if ((d & 3) == 1) r1 = fmaf(yv, yv, r1);
            else if ((d & 3) == 2) r2 = fmaf(yv, yv, r2);
            else r3 = fmaf(yv, yv, r3);
        }
        u[0] = sqrtf(1.0f + (r0 + r1) + (r2 + r3));  // projx time component

        // swizzled LDS write: float4 slot q = item*8 + (j ^ (item&7))
        #pragma unroll
        for (int j = 0; j < DD / 4; ++j) {
            int q = tid * 8 + (j ^ (tid & 7));
            reinterpret_cast<float4*>(lds)[q] =
                make_float4(u[4*j+0], u[4*j+1], u[4*j+2], u[4*j+3]);
        }
    }

    __syncthreads();

    // cooperative dense store: 2048 float4 = 256 KB-aligned contiguous region
    float4* obase = reinterpret_cast<float4*>(
        out + (size_t)s * ((size_t)n_items * DD) + (size_t)item0 * DD);
    #pragma unroll
    for (int c = 0; c < 8; ++c) {
        int f4   = c * 256 + tid;
        int it_r = f4 >> 3;                          // item within block
        int j    = tid & 7;                          // == f4 & 7
        if (item0 + it_r < n_items) {
            int q = it_r * 8 + (j ^ (it_r & 7));
            obase[f4] = reinterpret_cast<const float4*>(lds)[q];
        }
    }
}

// ============ K2: fusion, 4 lanes per item; h in registers, single read =====
#define GMV(o0,o1,o2,o3,o4, v0,v1,v2,v3,v4)                                   \
    o0 = fmaf(G00,(v0), fmaf(G01,(v1), fmaf(G02,(v2), fmaf(G03,(v3), nt0*(v4))))); \
    o1 = fmaf(G01,(v0), fmaf(G11,(v1), fmaf(G12,(v2), fmaf(G13,(v3), nt1*(v4))))); \
    o2 = fmaf(G02,(v0), fmaf(G12,(v1), fmaf(G22,(v2), fmaf(G23,(v3), nt2*(v4))))); \
    o3 = fmaf(G03,(v0), fmaf(G13,(v1), fmaf(G23,(v2), fmaf(G33,(v3), nt3*(v4))))); \
    o4 = fmaf(nt0,(v0), fmaf(nt1,(v1), fmaf(nt2,(v2), fmaf(nt3,(v3), -(v4)))));

#define DOT5(a0,a1,a2,a3,a4, c0,c1,c2,c3,c4) \
    fmaf((a0),(c0), fmaf((a1),(c1), fmaf((a2),(c2), fmaf((a3),(c3), (a4)*(c4)))))

__global__ __launch_bounds__(256)
void fusion_kernel(const float* __restrict__ lw,
                   float* __restrict__ out, int n_items)
{
    const int T    = blockIdx.x * blockDim.x + threadIdx.x;
    const int item = T >> 2;
    const int sub  = T & 3;
    if (item >= n_items) return;

    float l0 = lw[0], l1 = lw[1], l2 = lw[2], l3 = lw[3];
    float mxw = fmaxf(fmaxf(l0, l1), fmaxf(l2, l3));
    float e0 = __expf(l0 - mxw), e1 = __expf(l1 - mxw),
          e2 = __expf(l2 - mxw), e3 = __expf(l3 - mxw);
    float winv = frcp(e0 + e1 + e2 + e3);
    float w0 = e0 * winv, w1 = e1 * winv, w2 = e2 * winv, w3 = e3 * winv;

    const size_t osz = (size_t)n_items * DD;

    float hv[4][8];
    #pragma unroll
    for (int s = 0; s < 4; ++s) {
        const float4* p = reinterpret_cast<const float4*>(
            out + (size_t)s * osz + (size_t)item * DD + sub * 8);
        float4 a = p[0], b = p[1];
        hv[s][0] = a.x; hv[s][1] = a.y; hv[s][2] = a.z; hv[s][3] = a.w;
        hv[s][4] = b.x; hv[s][5] = b.y; hv[s][6] = b.z; hv[s][7] = b.w;
    }

    const float is0 = (sub == 0) ? 1.0f : 0.0f;
    float tau0 = qsum(is0 * hv[0][0]);
    float tau1 = qsum(is0 * hv[1][0]);
    float tau2 = qsum(is0 * hv[2][0]);
    float tau3 = qsum(is0 * hv[3][0]);

    float d00 = edot8(hv[0], hv[0]);
    float d01 = edot8(hv[0], hv[1]);
    float d02 = edot8(hv[0], hv[2]);
    float d03 = edot8(hv[0], hv[3]);
    float d11 = edot8(hv[1], hv[1]);
    float d12 = edot8(hv[1], hv[2]);
    float d13 = edot8(hv[1], hv[3]);
    float d22 = edot8(hv[2], hv[2]);
    float d23 = edot8(hv[2], hv[3]);
    float d33 = edot8(hv[3], hv[3]);

    float G00 = fmaf(-2.0f*tau0, tau0, d00);
    float G01 = fmaf(-2.0f*tau0, tau1, d01);
    float G02 = fmaf(-2.0f*tau0, tau2, d02);
    float G03 = fmaf(-2.0f*tau0, tau3, d03);
    float G11 = fmaf(-2.0f*tau1, tau1, d11);
    float G12 = fmaf(-2.0f*tau1, tau2, d12);
    float G13 = fmaf(-2.0f*tau1, tau3, d13);
    float G22 = fmaf(-2.0f*tau2, tau2, d22);
    float G23 = fmaf(-2.0f*tau2, tau3, d23);
    float G33 = fmaf(-2.0f*tau3, tau3, d33);
    float nt0 = -tau0, nt1 = -tau1, nt2 = -tau2, nt3 = -tau3;

    float b0v, b1v, b2v, b3v, b4v, g0, g1, g2, g3, g4;
    {
        float al0 = fmaxf(tau0, 1.0f + HEPS);
        float al1 = fmaxf(tau1, 1.0f + HEPS);
        float al2 = fmaxf(tau2, 1.0f + HEPS);
        float al3 = fmaxf(tau3, 1.0f + HEPS);
        float cc0 = w0 * acosh_coef(al0);
        float cc1 = w1 * acosh_coef(al1);
        float cc2 = w2 * acosh_coef(al2);
        float cc3 = w3 * acosh_coef(al3);
        b0v = cc0; b1v = cc1; b2v = cc2; b3v = cc3;
        b4v = -DOT5(cc0, cc1, cc2, cc3, 0.0f, al0, al1, al2, al3, 0.0f);

        GMV(g0, g1, g2, g3, g4, b0v, b1v, b2v, b3v, b4v);
        float gq = DOT5(g0, g1, g2, g3, g4, b0v, b1v, b2v, b3v, b4v);
        float sq = fmaxf(gq, 1e-12f);
        float nrm = sqrtf(sq);
        float ep = __expf(nrm), em = frcp(ep);
        float ch = 0.5f * (ep + em);
        float sc = 0.5f * (ep - em) * frcp(fmaxf(nrm, HEPS));
        b0v *= sc; b1v *= sc; b2v *= sc; b3v *= sc;
        b4v = fmaf(sc, b4v, ch);

        GMV(g0, g1, g2, g3, g4, b0v, b1v, b2v, b3v, b4v);
        float xx = DOT5(g0, g1, g2, g3, g4, b0v, b1v, b2v, b3v, b4v);
        float xt = DOT5(b0v, b1v, b2v, b3v, b4v, tau0, tau1, tau2, tau3, 1.0f);
        float tc = sqrtf(fmaf(xt, xt, 1.0f + xx));
        float dl = tc - xt;
        b4v += dl;
        g0 = fmaf(dl, nt0, g0); g1 = fmaf(dl, nt1, g1);
        g2 = fmaf(dl, nt2, g2); g3 = fmaf(dl, nt3, g3);
        g4 -= dl;
    }

    for (int it = 0; it < N_ITERS; ++it) {
        float al0 = fmaxf(-g0, 1.0f + HEPS);
        float al1 = fmaxf(-g1, 1.0f + HEPS);
        float al2 = fmaxf(-g2, 1.0f + HEPS);
        float al3 = fmaxf(-g3, 1.0f + HEPS);
        float cc0 = w0 * acosh_coef(al0);
        float cc1 = w1 * acosh_coef(al1);
        float cc2 = w2 * acosh_coef(al2);
        float cc3 = w3 * acosh_coef(al3);
        float S = DOT5(cc0, cc1, cc2, cc3, 0.0f, al0, al1, al2, al3, 0.0f);

        float gm0 = fmaf(-S, b0v, cc0);
        float gm1 = fmaf(-S, b1v, cc1);
        float gm2 = fmaf(-S, b2v, cc2);
        float gm3 = fmaf(-S, b3v, cc3);
        float gm4 = -S * b4v;

        float Gg0, Gg1, Gg2, Gg3, Gg4;
        GMV(Gg0, Gg1, Gg2, Gg3, Gg4, gm0, gm1, gm2, gm3, gm4);
        float qq = DOT5(Gg0, Gg1, Gg2, Gg3, Gg4, gm0, gm1, gm2, gm3, gm4);

        float sq = fmaxf(0.25f * qq, 1e-12f);
        float nrm = sqrtf(sq);
        float ep = __expf(nrm), em = frcp(ep);
        float ch = 0.5f * (ep + em);
        float sc = 0.25f * (ep - em) * frcp(fmaxf(nrm, HEPS));

        b0v = fmaf(ch, b0v, sc * gm0);
        b1v = fmaf(ch, b1v, sc * gm1);
        b2v = fmaf(ch, b2v, sc * gm2);
        b3v = fmaf(ch, b3v, sc * gm3);
        b4v = fmaf(ch, b4v, sc * gm4);
        g0  = fmaf(ch, g0, sc * Gg0);
        g1  = fmaf(ch, g1, sc * Gg1);
        g2  = fmaf(ch, g2, sc * Gg2);
        g3  = fmaf(ch, g3, sc * Gg3);
        g4  = fmaf(ch, g4, sc * Gg4);

        float xx = DOT5(g0, g1, g2, g3, g4, b0v, b1v, b2v, b3v, b4v);
        float xt = DOT5(b0v, b1v, b2v, b3v, b4v, tau0, tau1, tau2, tau3, 1.0f);
        float tc = sqrtf(fmaf(xt, xt, 1.0f + xx));
        float dl = tc - xt;
        b4v += dl;
        g0 = fmaf(dl, nt0, g0); g1 = fmaf(dl, nt1, g1);
        g2 = fmaf(dl, nt2, g2); g3 = fmaf(dl, nt3, g3);
        g4 -= dl;
    }

    float r[8];
    #pragma unroll
    for (int j = 0; j < 8; ++j)
        r[j] = fmaf(b0v, hv[0][j], fmaf(b1v, hv[1][j],
               fmaf(b2v, hv[2][j], b3v * hv[3][j])));
    if (sub == 0) r[0] += b4v;

    float4* po = reinterpret_cast<float4*>(
        out + (size_t)4 * osz + (size_t)item * DD + sub * 8);
    po[0] = make_float4(r[0], r[1], r[2], r[3]);
    po[1] = make_float4(r[4], r[5], r[6], r[7]);
}

extern "C" void kernel_launch(void* const* d_in, const int* in_sizes, int n_in,
                              void* d_out, int out_size, void* d_ws, size_t ws_size,
                              hipStream_t stream)
{
    const float* x0 = (const float*)d_in[0];
    const float* x1 = (const float*)d_in[1];
    const float* x2 = (const float*)d_in[2];
    const float* x3 = (const float*)d_in[3];
    const float* W0 = (const float*)d_in[4];
    const float* b0 = (const float*)d_in[5];
    const float* W1 = (const float*)d_in[6];
    const float* b1 = (const float*)d_in[7];
    const float* W2 = (const float*)d_in[8];
    const float* b2 = (const float*)d_in[9];
    const float* W3 = (const float*)d_in[10];
    const float* b3 = (const float*)d_in[11];
    const float* es = (const float*)d_in[12];
    const float* lw = (const float*)d_in[13];

    const int n_items = in_sizes[0] / SEG;   // 262144
    const int block = 256;

    prep_kernel<<<7, block, 0, stream>>>(W0, b0, W1, b1, W2, b2, W3, b3,
                                         es, (unsigned*)d_ws);

    const int gx = (n_items + block - 1) / block;
    dim3 grid1(gx, 4, 1);
    encode_kernel<<<grid1, block, 0, stream>>>(x0, x1, x2, x3,
                                               (const unsigned*)d_ws,
                                               (float*)d_out, n_items);

    const int n_threads = n_items * 4;
    const int gx2 = (n_threads + block - 1) / block;
    fusion_kernel<<<gx2, block, 0, stream>>>(lw, (float*)d_out, n_items);
}